// Round 4
// baseline (36.167 us; speedup 1.0000x reference)
//
#include <hip/hip_runtime.h>

// Output: [64, 2050, 14, 14] fp32.
// Channels [0,2048) = copy of img_feat; ch 2048 = x-map (j*2/14-1); ch 2049 = y-map (i*2/14-1).
// Per channel = 196 floats = 49 float4s. Per-batch: img = 2048*49 = 100352 float4s,
// out = 2050*49 = 100450 float4s. All bases 16B-aligned.
//
// Grid: (49, 64). blockIdx.y = batch, blockIdx.x = 2048-float4 chunk (256 thr x 8).
// 8 loads batched into registers, then 8 nt stores: longer same-direction DRAM
// bursts + 8 in-flight loads per thread.

typedef float f4 __attribute__((ext_vector_type(4)));

#define B_IMG4 100352  // 2048*49
#define B_OUT4 100450  // 2050*49

__global__ __launch_bounds__(256) void AddSpatialInfo_kernel(
    const f4* __restrict__ in, f4* __restrict__ out) {
  const int b = blockIdx.y;
  const int t = threadIdx.x;
  const int inBase  = b * B_IMG4 + blockIdx.x * 2048 + t;
  const int outBase = b * B_OUT4 + blockIdx.x * 2048 + t;
  f4 v[8];
#pragma unroll
  for (int k = 0; k < 8; ++k) v[k] = in[inBase + k * 256];
#pragma unroll
  for (int k = 0; k < 8; ++k)
    __builtin_nontemporal_store(v[k], &out[outBase + k * 256]);
  // Coord channels: 2 ch x 49 float4s = 98 float4s per batch, done by block x==0.
  if (blockIdx.x == 0 && t < 98) {
    const int ch = t / 49;        // 0 -> x channel, 1 -> y channel
    const int p4 = t - ch * 49;   // float4 index within channel
    f4 c;
#pragma unroll
    for (int m = 0; m < 4; ++m) {
      int p = p4 * 4 + m;         // 0..195
      int i = p / 14, j = p - i * 14;
      c[m] = (ch == 0) ? (j * 2.0f / 14.0f - 1.0f)
                       : (i * 2.0f / 14.0f - 1.0f);
    }
    __builtin_nontemporal_store(c, &out[b * B_OUT4 + B_IMG4 + t]);
  }
}

extern "C" void kernel_launch(void* const* d_in, const int* in_sizes, int n_in,
                              void* d_out, int out_size, void* d_ws, size_t ws_size,
                              hipStream_t stream) {
  const f4* in = (const f4*)d_in[0];
  f4* out = (f4*)d_out;
  dim3 grid(49, 64);  // 49 chunks of 2048 float4s cover 100352 float4s per batch
  AddSpatialInfo_kernel<<<grid, 256, 0, stream>>>(in, out);
}

// Round 5
// 35.109 us; speedup vs baseline: 1.0301x; 1.0301x over previous
//
#include <hip/hip_runtime.h>

// Output: [64, 2050, 14, 14] fp32.
// Channels [0,2048) = copy of img_feat; ch 2048 = x-map (j*2/14-1); ch 2049 = y-map (i*2/14-1).
// Per channel = 196 floats = 49 float4s. Per-batch: img = 2048*49 = 100352 float4s,
// out = 2050*49 = 100450 float4s. All bases 16B-aligned.
//
// Grid: (49, 64). blockIdx.y = batch, blockIdx.x = 2048-float4 chunk (256 thr x 8).
// A/B vs round 4: REGULAR stores (allow L3 write residency across replays)
// instead of nontemporal. Everything else identical.

typedef float f4 __attribute__((ext_vector_type(4)));

#define B_IMG4 100352  // 2048*49
#define B_OUT4 100450  // 2050*49

__global__ __launch_bounds__(256) void AddSpatialInfo_kernel(
    const f4* __restrict__ in, f4* __restrict__ out) {
  const int b = blockIdx.y;
  const int t = threadIdx.x;
  const int inBase  = b * B_IMG4 + blockIdx.x * 2048 + t;
  const int outBase = b * B_OUT4 + blockIdx.x * 2048 + t;
  f4 v[8];
#pragma unroll
  for (int k = 0; k < 8; ++k) v[k] = in[inBase + k * 256];
#pragma unroll
  for (int k = 0; k < 8; ++k) out[outBase + k * 256] = v[k];
  // Coord channels: 2 ch x 49 float4s = 98 float4s per batch, done by block x==0.
  if (blockIdx.x == 0 && t < 98) {
    const int ch = t / 49;        // 0 -> x channel, 1 -> y channel
    const int p4 = t - ch * 49;   // float4 index within channel
    f4 c;
#pragma unroll
    for (int m = 0; m < 4; ++m) {
      int p = p4 * 4 + m;         // 0..195
      int i = p / 14, j = p - i * 14;
      c[m] = (ch == 0) ? (j * 2.0f / 14.0f - 1.0f)
                       : (i * 2.0f / 14.0f - 1.0f);
    }
    out[b * B_OUT4 + B_IMG4 + t] = c;
  }
}

extern "C" void kernel_launch(void* const* d_in, const int* in_sizes, int n_in,
                              void* d_out, int out_size, void* d_ws, size_t ws_size,
                              hipStream_t stream) {
  const f4* in = (const f4*)d_in[0];
  f4* out = (f4*)d_out;
  dim3 grid(49, 64);  // 49 chunks of 2048 float4s cover 100352 float4s per batch
  AddSpatialInfo_kernel<<<grid, 256, 0, stream>>>(in, out);
}

// Round 6
// 34.914 us; speedup vs baseline: 1.0359x; 1.0056x over previous
//
#include <hip/hip_runtime.h>

// Output: [64, 2050, 14, 14] fp32.
// Channels [0,2048) = copy of img_feat; ch 2048 = x-map (j*2/14-1); ch 2049 = y-map (i*2/14-1).
// Per channel = 196 floats = 49 float4s. Per-batch: img = 2048*49 = 100352 float4s,
// out = 2050*49 = 100450 float4s. All bases 16B-aligned.
//
// Grid: (98, 64) = 6272 blocks (24.5/CU -> ~2% tail quantization vs 6% at 3136).
// 4-deep batched loads then 4 REGULAR stores (L3 write residency: +1us vs nt,
// measured round 4->5).

typedef float f4 __attribute__((ext_vector_type(4)));

#define B_IMG4 100352  // 2048*49
#define B_OUT4 100450  // 2050*49

__global__ __launch_bounds__(256) void AddSpatialInfo_kernel(
    const f4* __restrict__ in, f4* __restrict__ out) {
  const int b = blockIdx.y;
  const int t = threadIdx.x;
  const int inBase  = b * B_IMG4 + blockIdx.x * 1024 + t;
  const int outBase = b * B_OUT4 + blockIdx.x * 1024 + t;
  f4 v[4];
#pragma unroll
  for (int k = 0; k < 4; ++k) v[k] = in[inBase + k * 256];
#pragma unroll
  for (int k = 0; k < 4; ++k) out[outBase + k * 256] = v[k];
  // Coord channels: 2 ch x 49 float4s = 98 float4s per batch, done by block x==0.
  if (blockIdx.x == 0 && t < 98) {
    const int ch = t / 49;        // 0 -> x channel, 1 -> y channel
    const int p4 = t - ch * 49;   // float4 index within channel
    f4 c;
#pragma unroll
    for (int m = 0; m < 4; ++m) {
      int p = p4 * 4 + m;         // 0..195
      int i = p / 14, j = p - i * 14;
      c[m] = (ch == 0) ? (j * 2.0f / 14.0f - 1.0f)
                       : (i * 2.0f / 14.0f - 1.0f);
    }
    out[b * B_OUT4 + B_IMG4 + t] = c;
  }
}

extern "C" void kernel_launch(void* const* d_in, const int* in_sizes, int n_in,
                              void* d_out, int out_size, void* d_ws, size_t ws_size,
                              hipStream_t stream) {
  const f4* in = (const f4*)d_in[0];
  f4* out = (f4*)d_out;
  dim3 grid(98, 64);  // 98 chunks of 1024 float4s cover 100352 float4s per batch
  AddSpatialInfo_kernel<<<grid, 256, 0, stream>>>(in, out);
}